// Round 1
// baseline (820.697 us; speedup 1.0000x reference)
//
#include <hip/hip_runtime.h>
#include <math.h>

#define CIN    64
#define KOUT   128
#define HGT    128
#define WID    128
#define NBATCH 16
#define CB     4     // input channels per LDS chunk
#define TH     8     // output rows per block
#define KB     8     // output channels per block
#define BN_EPS 1e-5f

// ---------------- Kernel A: w_scale = max|W| (atomicMax on float bits) ------
__global__ __launch_bounds__(256) void wmax_kernel(const float* __restrict__ W,
                                                   unsigned* __restrict__ wsmax) {
    int idx = blockIdx.x * 256 + threadIdx.x;   // 72*256 threads, 1 float4 each
    const float4* W4 = (const float4*)W;
    float4 v = W4[idx];
    float m = fmaxf(fmaxf(fabsf(v.x), fabsf(v.y)), fmaxf(fabsf(v.z), fabsf(v.w)));
    #pragma unroll
    for (int off = 32; off > 0; off >>= 1)
        m = fmaxf(m, __shfl_xor(m, off));
    __shared__ float red[4];
    if ((threadIdx.x & 63) == 0) red[threadIdx.x >> 6] = m;
    __syncthreads();
    if (threadIdx.x == 0) {
        m = fmaxf(fmaxf(red[0], red[1]), fmaxf(red[2], red[3]));
        atomicMax(wsmax, __float_as_uint(m));   // all values >= 0: uint order == float order
    }
}

// ---------------- Kernel B: conv3x3 + BN + ReLU + uint8 act quant -----------
// grid = 4096: bid = (n<<8) | (kg<<4) | hg
__global__ __launch_bounds__(256) void conv_kernel(
    const float* __restrict__ x, const float* __restrict__ W,
    const float* __restrict__ gamma, const float* __restrict__ beta,
    const float* __restrict__ mean, const float* __restrict__ var,
    const float* __restrict__ act_scale, const unsigned* __restrict__ wsmax,
    float* __restrict__ out)
{
    __shared__ float xs[CB][TH + 2][WID + 2];   // 4*10*130*4B = 20.8 KB
    __shared__ float wsh[CB][9][KB];            // dequantized weights, 1.15 KB

    const int bid = blockIdx.x;
    const int hg = bid & 15;
    const int kg = (bid >> 4) & 15;
    const int n  = bid >> 8;
    const int h0 = hg * TH;
    const int k0 = kg * KB;

    const int tid = threadIdx.x;
    const int tx = tid & 31;    // w base (interleaved: w = tx + 32*j)
    const int ty = tid >> 5;    // output row within tile, 0..7

    float acc[4][KB];
    #pragma unroll
    for (int j = 0; j < 4; ++j)
        #pragma unroll
        for (int kk = 0; kk < KB; ++kk) acc[j][kk] = 0.f;

    const float w_scale = __uint_as_float(*wsmax) / 127.0f;
    const float* xn = x + (size_t)n * CIN * HGT * WID;

    for (int c0 = 0; c0 < CIN; c0 += CB) {
        __syncthreads();   // protect xs/wsh from previous chunk's readers
        // ---- stage x tile: rows h0-1..h0+TH, cols -1..WID (zero pad) ----
        for (int i = tid; i < CB * (TH + 2) * (WID + 2); i += 256) {
            int cc = i / ((TH + 2) * (WID + 2));
            int r  = i - cc * ((TH + 2) * (WID + 2));
            int yy = r / (WID + 2);
            int xx = r - yy * (WID + 2);
            int gh = h0 - 1 + yy;
            int gw = xx - 1;
            float v = 0.f;
            if ((unsigned)gh < HGT && (unsigned)gw < WID)
                v = xn[(size_t)(c0 + cc) * HGT * WID + gh * WID + gw];
            xs[cc][yy][xx] = v;
        }
        // ---- stage weights, quant-dequant exactly like the reference ----
        for (int i = tid; i < CB * 9 * KB; i += 256) {
            int cc  = i / (9 * KB);
            int r   = i - cc * (9 * KB);
            int tap = r / KB;
            int kk  = r - tap * KB;
            float w = W[(size_t)((k0 + kk) * CIN + (c0 + cc)) * 9 + tap];
            float q = rintf(w / w_scale);            // RNE == jnp.round
            q = fminf(fmaxf(q, -127.f), 127.f);
            wsh[cc][tap][kk] = q * w_scale;
        }
        __syncthreads();
        // ---- compute ----
        #pragma unroll
        for (int cc = 0; cc < CB; ++cc) {
            #pragma unroll
            for (int dy = 0; dy < 3; ++dy) {
                float w0[KB], w1[KB], w2[KB];
                #pragma unroll
                for (int kk = 0; kk < KB; ++kk) {
                    w0[kk] = wsh[cc][dy * 3 + 0][kk];
                    w1[kk] = wsh[cc][dy * 3 + 1][kk];
                    w2[kk] = wsh[cc][dy * 3 + 2][kk];
                }
                const float* row = &xs[cc][ty + dy][0];
                #pragma unroll
                for (int j = 0; j < 4; ++j) {
                    int base = tx + 32 * j;   // xs col = out_w + dx, dx in 0..2
                    float v0 = row[base + 0];
                    float v1 = row[base + 1];
                    float v2 = row[base + 2];
                    #pragma unroll
                    for (int kk = 0; kk < KB; ++kk) {
                        acc[j][kk] = fmaf(v0, w0[kk], acc[j][kk]);
                        acc[j][kk] = fmaf(v1, w1[kk], acc[j][kk]);
                        acc[j][kk] = fmaf(v2, w2[kk], acc[j][kk]);
                    }
                }
            }
        }
    }

    // ---- epilogue: BN + ReLU + uint8 quant-dequant ----
    const float s_act = act_scale[0] / 255.0f;
    const float inv_s = 1.0f / s_act;
    const int h = h0 + ty;
    #pragma unroll
    for (int kk = 0; kk < KB; ++kk) {
        int k = k0 + kk;
        float isd = 1.0f / sqrtf(var[k] + BN_EPS);
        float sc = gamma[k] * isd;
        float sh = beta[k] - gamma[k] * mean[k] * isd;
        float* orow = out + (((size_t)n * KOUT + k) * HGT + h) * WID;
        #pragma unroll
        for (int j = 0; j < 4; ++j) {
            float y = fmaf(acc[j][kk], sc, sh);
            y = fmaxf(y, 0.f);                 // ReLU
            float q = rintf(y * inv_s);        // round-half-even
            q = fminf(q, 255.f);               // y>=0 so lower clip is free
            orow[tx + 32 * j] = q * s_act;
        }
    }
}

extern "C" void kernel_launch(void* const* d_in, const int* in_sizes, int n_in,
                              void* d_out, int out_size, void* d_ws, size_t ws_size,
                              hipStream_t stream) {
    const float* x         = (const float*)d_in[0];
    const float* W         = (const float*)d_in[1];
    const float* gamma     = (const float*)d_in[2];
    const float* beta      = (const float*)d_in[3];
    const float* mean      = (const float*)d_in[4];
    const float* var       = (const float*)d_in[5];
    const float* act_scale = (const float*)d_in[6];
    unsigned* wsmax = (unsigned*)d_ws;

    hipMemsetAsync(d_ws, 0, sizeof(unsigned), stream);   // capture-safe memset node
    wmax_kernel<<<72, 256, 0, stream>>>(W, wsmax);       // 72*256*4 = 73728 elements
    conv_kernel<<<dim3(4096), dim3(256), 0, stream>>>(
        x, W, gamma, beta, mean, var, act_scale, wsmax, (float*)d_out);
}

// Round 2
// 160.141 us; speedup vs baseline: 5.1248x; 5.1248x over previous
//
#include <hip/hip_runtime.h>
#include <math.h>

typedef __bf16 bf16x8 __attribute__((ext_vector_type(8)));
typedef float  f32x16 __attribute__((ext_vector_type(16)));

#define CIN    64
#define KOUT   128
#define HGT    128
#define WID    128
#define NBATCH 16
#define BN_EPS 1e-5f

// workspace layout
#define WQ_OFF   256u                        // 9*128*64 bf16 = 147456 B
#define XT_OFF   (1u << 20)                  // NHWC bf16 x: 16*128*128*64*2 = 33554432 B
#define WS_NEED  ((size_t)XT_OFF + (size_t)NBATCH * HGT * WID * CIN * 2)

// ---------------- w_scale = max|W| ------------------------------------------
__global__ __launch_bounds__(256) void wmax_kernel(const float* __restrict__ W,
                                                   unsigned* __restrict__ wsmax) {
    int idx = blockIdx.x * 256 + threadIdx.x;   // 72*256*4 = 73728 floats
    const float4* W4 = (const float4*)W;
    float4 v = W4[idx];
    float m = fmaxf(fmaxf(fabsf(v.x), fabsf(v.y)), fmaxf(fabsf(v.z), fabsf(v.w)));
    #pragma unroll
    for (int off = 32; off > 0; off >>= 1)
        m = fmaxf(m, __shfl_xor(m, off));
    __shared__ float red[4];
    if ((threadIdx.x & 63) == 0) red[threadIdx.x >> 6] = m;
    __syncthreads();
    if (threadIdx.x == 0) {
        m = fmaxf(fmaxf(red[0], red[1]), fmaxf(red[2], red[3]));
        atomicMax(wsmax, __float_as_uint(m));
    }
}

// ---------------- pack weights: integer-valued bf16 Wq[tap][k][c] -----------
__global__ __launch_bounds__(256) void pack_w(const float* __restrict__ W,
                                              const unsigned* __restrict__ wsmax,
                                              __bf16* __restrict__ wq) {
    int o = blockIdx.x * 256 + threadIdx.x;     // 288*256 = 73728
    float ws = __uint_as_float(*wsmax) / 127.0f;
    int c   = o & 63;
    int k   = (o >> 6) & 127;
    int tap = o >> 13;
    float w = W[(size_t)(k * 64 + c) * 9 + tap];
    float q = rintf(w / ws);                    // RNE, matches jnp.round
    q = fminf(fmaxf(q, -127.f), 127.f);
    wq[o] = (__bf16)q;                          // integer: exact in bf16
}

// ---------------- x: NCHW f32 -> NHWC bf16 -----------------------------------
__global__ __launch_bounds__(256) void xform(const float* __restrict__ x,
                                             __bf16* __restrict__ xT) {
    __shared__ float t[CIN * 32];               // 8 KB, xor-swizzled cols
    int bid = blockIdx.x;                       // n*512 + h*4 + wt
    int wt = bid & 3;
    int h  = (bid >> 2) & 127;
    int n  = bid >> 9;
    int w0 = wt * 32;
    int tid = threadIdx.x;
    const float* src = x + ((size_t)n * CIN * HGT + h) * WID + w0;
    int wlane = tid & 31;
    int cbase = tid >> 5;
    #pragma unroll
    for (int it = 0; it < 8; ++it) {
        int c = cbase + it * 8;
        t[c * 32 + (wlane ^ (c & 31))] = src[(size_t)c * HGT * WID + wlane];
    }
    __syncthreads();
    int w = tid >> 3;
    int chunk = tid & 7;
    bf16x8 o;
    #pragma unroll
    for (int j = 0; j < 8; ++j) {
        int c = chunk * 8 + j;
        o[j] = (__bf16)t[c * 32 + (w ^ (c & 31))];
    }
    *(bf16x8*)(xT + (((size_t)n * HGT + h) * WID + w0 + w) * CIN + chunk * 8) = o;
}

// ---------------- conv3x3 via MFMA 32x32x16 bf16 ----------------------------
// block: 256 thr = 4 waves; tile 16h x 16w pixels, all 128 kout.
// wave: 64 pixels (2 N-frags of 32) x 128 kout (4 M-frags of 32).
__global__ __launch_bounds__(256, 2) void conv_mfma(
    const __bf16* __restrict__ xT, const __bf16* __restrict__ wq,
    const float* __restrict__ gamma, const float* __restrict__ beta,
    const float* __restrict__ mean, const float* __restrict__ var,
    const float* __restrict__ act_scale, const unsigned* __restrict__ wsmax,
    float* __restrict__ out)
{
    __shared__ uint4 xs[2592];                  // 18*18 pixels * 8 chunks * 16B = 41.5 KB
    __shared__ float sc2[KOUT], sh2[KOUT];

    const int bid = blockIdx.x;                 // n*64 + hb*8 + wb
    const int wb = bid & 7, hb = (bid >> 3) & 7, n = bid >> 6;
    const int h0 = hb * 16, w0 = wb * 16;
    const int tid  = threadIdx.x;
    const int lane = tid & 63;
    const int wave = tid >> 6;

    const float s_act = act_scale[0] / 255.0f;
    if (tid < KOUT) {
        float ws  = __uint_as_float(*wsmax) / 127.0f;
        float isd = 1.0f / sqrtf(var[tid] + BN_EPS);
        float sc  = ws * gamma[tid] * isd;      // fold w_scale into BN scale
        float sh  = beta[tid] - gamma[tid] * mean[tid] * isd;
        sc2[tid] = sc / s_act;                  // fold 1/s_act: q = rint(acc*sc2+sh2)
        sh2[tid] = sh / s_act;
    }

    // ---- stage halo tile 18x18 pixels x 64 ch, chunk-xor swizzle ----
    const __bf16* xn = xT + (size_t)n * HGT * WID * CIN;
    for (int it = tid; it < 2592; it += 256) {
        int pl = it >> 3, chunk = it & 7;
        int r = pl / 18, cc = pl - r * 18;
        int gh = h0 - 1 + r, gw = w0 - 1 + cc;
        uint4 v = make_uint4(0u, 0u, 0u, 0u);
        if ((unsigned)gh < HGT && (unsigned)gw < WID)
            v = *(const uint4*)(xn + ((size_t)gh * WID + gw) * CIN + chunk * 8);
        xs[pl * 8 + (chunk ^ (pl & 7))] = v;
    }
    __syncthreads();

    const int nn = lane & 31;                   // pixel within frag
    const int kh = lane >> 5;                   // k-half (channels +8)
    const int rl = nn >> 4;                     // local row 0/1
    const int wl = nn & 15;
    const int hloc = (wave << 2) + rl;          // wave owns 4 h-rows
    const int pl_b0 = hloc * 18 + wl;           // pf=0 pixel-linear base (tap 0,0)
    const int pl_b1 = (hloc + 2) * 18 + wl;     // pf=1

    const __bf16* wlp = wq + (size_t)(lane & 31) * 64 + kh * 8;

    f32x16 acc[4][2];
    #pragma unroll
    for (int a = 0; a < 4; ++a)
        #pragma unroll
        for (int b = 0; b < 2; ++b)
            #pragma unroll
            for (int r = 0; r < 16; ++r) acc[a][b][r] = 0.0f;

    for (int cs = 0; cs < 4; ++cs) {            // channel steps of 16
        const int chb = cs * 2 + kh;            // base 16B-chunk index
        const int cel = cs * 16;                // channel element offset
        #pragma unroll
        for (int tap = 0; tap < 9; ++tap) {
            const int dy = tap / 3, dx = tap - dy * 3;   // constants post-unroll
            const __bf16* wp = wlp + (size_t)tap * 8192 + cel;  // tap*128*64
            bf16x8 a0 = *(const bf16x8*)(wp);
            bf16x8 a1 = *(const bf16x8*)(wp + 32 * 64);
            bf16x8 a2 = *(const bf16x8*)(wp + 64 * 64);
            bf16x8 a3 = *(const bf16x8*)(wp + 96 * 64);
            const int pl0 = pl_b0 + dy * 18 + dx;
            const int pl1 = pl_b1 + dy * 18 + dx;
            bf16x8 b0 = *(const bf16x8*)&xs[pl0 * 8 + (chb ^ (pl0 & 7))];
            bf16x8 b1 = *(const bf16x8*)&xs[pl1 * 8 + (chb ^ (pl1 & 7))];
            acc[0][0] = __builtin_amdgcn_mfma_f32_32x32x16_bf16(a0, b0, acc[0][0], 0, 0, 0);
            acc[0][1] = __builtin_amdgcn_mfma_f32_32x32x16_bf16(a0, b1, acc[0][1], 0, 0, 0);
            acc[1][0] = __builtin_amdgcn_mfma_f32_32x32x16_bf16(a1, b0, acc[1][0], 0, 0, 0);
            acc[1][1] = __builtin_amdgcn_mfma_f32_32x32x16_bf16(a1, b1, acc[1][1], 0, 0, 0);
            acc[2][0] = __builtin_amdgcn_mfma_f32_32x32x16_bf16(a2, b0, acc[2][0], 0, 0, 0);
            acc[2][1] = __builtin_amdgcn_mfma_f32_32x32x16_bf16(a2, b1, acc[2][1], 0, 0, 0);
            acc[3][0] = __builtin_amdgcn_mfma_f32_32x32x16_bf16(a3, b0, acc[3][0], 0, 0, 0);
            acc[3][1] = __builtin_amdgcn_mfma_f32_32x32x16_bf16(a3, b1, acc[3][1], 0, 0, 0);
        }
    }

    // ---- epilogue: BN + ReLU + uint8 quant-dequant ----
    const int wpix = w0 + wl;
    #pragma unroll
    for (int kf = 0; kf < 4; ++kf) {
        #pragma unroll
        for (int pf = 0; pf < 2; ++pf) {
            const int hpix = h0 + hloc + pf * 2;
            #pragma unroll
            for (int reg = 0; reg < 16; ++reg) {
                int k = kf * 32 + 4 * kh + (reg & 3) + 8 * (reg >> 2);
                float t = fmaf(acc[kf][pf][reg], sc2[k], sh2[k]);  // (conv*bn)/s_act
                t = fmaxf(t, 0.0f);                                 // relu (s_act>0)
                float q = fminf(rintf(t), 255.0f);
                out[(((size_t)n * KOUT + k) * HGT + hpix) * WID + wpix] = q * s_act;
            }
        }
    }
}

// ---------------- fallback (round-1 fp32 path, used only if ws too small) ---
#define CB 4
#define TH 8
#define KB 8
__global__ __launch_bounds__(256) void conv_fallback(
    const float* __restrict__ x, const float* __restrict__ W,
    const float* __restrict__ gamma, const float* __restrict__ beta,
    const float* __restrict__ mean, const float* __restrict__ var,
    const float* __restrict__ act_scale, const unsigned* __restrict__ wsmax,
    float* __restrict__ out)
{
    __shared__ float xsf[CB][TH + 2][WID + 2];
    __shared__ float wsh[CB][9][KB];
    const int bid = blockIdx.x;
    const int hg = bid & 15, kg = (bid >> 4) & 15, n = bid >> 8;
    const int h0 = hg * TH, k0 = kg * KB;
    const int tid = threadIdx.x;
    const int tx = tid & 31, ty = tid >> 5;
    float acc[4][KB];
    #pragma unroll
    for (int j = 0; j < 4; ++j)
        #pragma unroll
        for (int kk = 0; kk < KB; ++kk) acc[j][kk] = 0.f;
    const float w_scale = __uint_as_float(*wsmax) / 127.0f;
    const float* xn = x + (size_t)n * CIN * HGT * WID;
    for (int c0 = 0; c0 < CIN; c0 += CB) {
        __syncthreads();
        for (int i = tid; i < CB * (TH + 2) * (WID + 2); i += 256) {
            int cc = i / ((TH + 2) * (WID + 2));
            int r  = i - cc * ((TH + 2) * (WID + 2));
            int yy = r / (WID + 2);
            int xx = r - yy * (WID + 2);
            int gh = h0 - 1 + yy, gw = xx - 1;
            float v = 0.f;
            if ((unsigned)gh < HGT && (unsigned)gw < WID)
                v = xn[(size_t)(c0 + cc) * HGT * WID + gh * WID + gw];
            xsf[cc][yy][xx] = v;
        }
        for (int i = tid; i < CB * 9 * KB; i += 256) {
            int cc = i / (9 * KB);
            int r  = i - cc * (9 * KB);
            int tap = r / KB, kk = r - tap * KB;
            float w = W[(size_t)((k0 + kk) * CIN + (c0 + cc)) * 9 + tap];
            float q = rintf(w / w_scale);
            q = fminf(fmaxf(q, -127.f), 127.f);
            wsh[cc][tap][kk] = q * w_scale;
        }
        __syncthreads();
        #pragma unroll
        for (int cc = 0; cc < CB; ++cc)
            #pragma unroll
            for (int dy = 0; dy < 3; ++dy) {
                float w0a[KB], w1a[KB], w2a[KB];
                #pragma unroll
                for (int kk = 0; kk < KB; ++kk) {
                    w0a[kk] = wsh[cc][dy * 3 + 0][kk];
                    w1a[kk] = wsh[cc][dy * 3 + 1][kk];
                    w2a[kk] = wsh[cc][dy * 3 + 2][kk];
                }
                const float* row = &xsf[cc][ty + dy][0];
                #pragma unroll
                for (int j = 0; j < 4; ++j) {
                    float v0 = row[tx + 32 * j + 0];
                    float v1 = row[tx + 32 * j + 1];
                    float v2 = row[tx + 32 * j + 2];
                    #pragma unroll
                    for (int kk = 0; kk < KB; ++kk) {
                        acc[j][kk] = fmaf(v0, w0a[kk], acc[j][kk]);
                        acc[j][kk] = fmaf(v1, w1a[kk], acc[j][kk]);
                        acc[j][kk] = fmaf(v2, w2a[kk], acc[j][kk]);
                    }
                }
            }
    }
    const float s_act = act_scale[0] / 255.0f;
    const float inv_s = 1.0f / s_act;
    const int h = h0 + ty;
    #pragma unroll
    for (int kk = 0; kk < KB; ++kk) {
        int k = k0 + kk;
        float isd = 1.0f / sqrtf(var[k] + BN_EPS);
        float sc = gamma[k] * isd;
        float sh = beta[k] - gamma[k] * mean[k] * isd;
        float* orow = out + (((size_t)n * KOUT + k) * HGT + h) * WID;
        #pragma unroll
        for (int j = 0; j < 4; ++j) {
            float y = fmaf(acc[j][kk], sc, sh);
            y = fmaxf(y, 0.f);
            float q = rintf(y * inv_s);
            q = fminf(q, 255.f);
            orow[tx + 32 * j] = q * s_act;
        }
    }
}

extern "C" void kernel_launch(void* const* d_in, const int* in_sizes, int n_in,
                              void* d_out, int out_size, void* d_ws, size_t ws_size,
                              hipStream_t stream) {
    const float* x         = (const float*)d_in[0];
    const float* W         = (const float*)d_in[1];
    const float* gamma     = (const float*)d_in[2];
    const float* beta      = (const float*)d_in[3];
    const float* mean      = (const float*)d_in[4];
    const float* var       = (const float*)d_in[5];
    const float* act_scale = (const float*)d_in[6];
    unsigned* wsmax = (unsigned*)d_ws;

    hipMemsetAsync(d_ws, 0, sizeof(unsigned), stream);
    wmax_kernel<<<72, 256, 0, stream>>>(W, wsmax);

    if (ws_size >= WS_NEED) {
        __bf16* wq = (__bf16*)((char*)d_ws + WQ_OFF);
        __bf16* xT = (__bf16*)((char*)d_ws + XT_OFF);
        pack_w<<<288, 256, 0, stream>>>(W, wsmax, wq);
        xform<<<NBATCH * HGT * 4, 256, 0, stream>>>(x, xT);
        conv_mfma<<<NBATCH * 64, 256, 0, stream>>>(
            xT, wq, gamma, beta, mean, var, act_scale, wsmax, (float*)d_out);
    } else {
        conv_fallback<<<4096, 256, 0, stream>>>(
            x, W, gamma, beta, mean, var, act_scale, wsmax, (float*)d_out);
    }
}

// Round 3
// 86.491 us; speedup vs baseline: 9.4888x; 1.8515x over previous
//
#include <hip/hip_runtime.h>
#include <math.h>

typedef __bf16 bf16x8 __attribute__((ext_vector_type(8)));
typedef float  f32x16 __attribute__((ext_vector_type(16)));

#define CIN    64
#define KOUT   128
#define HGT    128
#define WID    128
#define NBATCH 16
#define BN_EPS 1e-5f

// workspace layout
#define WQ_OFF   256u                        // packed frag weights: 36*4*64*16B = 147456 B
#define XT_OFF   (1u << 20)                  // NHWC bf16 x: 16*128*128*64*2 = 33554432 B
#define WS_NEED  ((size_t)XT_OFF + (size_t)NBATCH * HGT * WID * CIN * 2)

// ---------------- w_scale = max|W| ------------------------------------------
__global__ __launch_bounds__(256) void wmax_kernel(const float* __restrict__ W,
                                                   unsigned* __restrict__ wsmax) {
    int idx = blockIdx.x * 256 + threadIdx.x;   // 72*256*4 = 73728 floats
    const float4* W4 = (const float4*)W;
    float4 v = W4[idx];
    float m = fmaxf(fmaxf(fabsf(v.x), fabsf(v.y)), fmaxf(fabsf(v.z), fabsf(v.w)));
    #pragma unroll
    for (int off = 32; off > 0; off >>= 1)
        m = fmaxf(m, __shfl_xor(m, off));
    __shared__ float red[4];
    if ((threadIdx.x & 63) == 0) red[threadIdx.x >> 6] = m;
    __syncthreads();
    if (threadIdx.x == 0) {
        m = fmaxf(fmaxf(red[0], red[1]), fmaxf(red[2], red[3]));
        atomicMax(wsmax, __float_as_uint(m));
    }
}

// ---------------- pack weights into MFMA A-fragment order -------------------
// wqp element base ((cs*9+tap)*4 + mf)*64 + lane  (bf16x8 per lane):
//   j-th elem = Wq[kout = mf*32 + (lane&31)][c = cs*16 + (lane>>5)*8 + j] at tap.
// A-frag load in conv = single coalesced 16B/lane read.
__global__ __launch_bounds__(256) void pack_w(const float* __restrict__ W,
                                              const unsigned* __restrict__ wsmax,
                                              __bf16* __restrict__ wqp) {
    int bid = blockIdx.x;                       // 36 = cs*9 + tap
    int tap = bid % 9, cs = bid / 9;
    int t = threadIdx.x;
    int lane = t & 63, mf = t >> 6;
    float ws = __uint_as_float(*wsmax) / 127.0f;
    int kout  = mf * 32 + (lane & 31);
    int cbase = cs * 16 + (lane >> 5) * 8;
    bf16x8 o;
    #pragma unroll
    for (int j = 0; j < 8; ++j) {
        float w = W[(size_t)(kout * 64 + cbase + j) * 9 + tap];
        float q = rintf(w / ws);                // RNE == jnp.round
        q = fminf(fmaxf(q, -127.f), 127.f);
        o[j] = (__bf16)q;                       // integer: exact in bf16
    }
    *(bf16x8*)(wqp + (((size_t)bid * 4 + mf) * 64 + lane) * 8) = o;
}

// ---------------- x: NCHW f32 -> NHWC bf16 -----------------------------------
__global__ __launch_bounds__(256) void xform(const float* __restrict__ x,
                                             __bf16* __restrict__ xT) {
    __shared__ float t[CIN * 32];               // 8 KB, xor-swizzled cols
    int bid = blockIdx.x;                       // n*512 + h*4 + wt
    int wt = bid & 3;
    int h  = (bid >> 2) & 127;
    int n  = bid >> 9;
    int w0 = wt * 32;
    int tid = threadIdx.x;
    const float* src = x + ((size_t)n * CIN * HGT + h) * WID + w0;
    int wlane = tid & 31;
    int cbase = tid >> 5;
    #pragma unroll
    for (int it = 0; it < 8; ++it) {
        int c = cbase + it * 8;
        t[c * 32 + (wlane ^ (c & 31))] = src[(size_t)c * HGT * WID + wlane];
    }
    __syncthreads();
    int w = tid >> 3;
    int chunk = tid & 7;
    bf16x8 o;
    #pragma unroll
    for (int j = 0; j < 8; ++j) {
        int c = chunk * 8 + j;
        o[j] = (__bf16)t[c * 32 + (w ^ (c & 31))];
    }
    *(bf16x8*)(xT + (((size_t)n * HGT + h) * WID + w0 + w) * CIN + chunk * 8) = o;
}

// ---------------- conv3x3 via MFMA 32x32x16 bf16 ----------------------------
// block: 256 thr = 4 waves; out tile 16h x 16w pixels x 128 kout.
// wave (wm = wave&1, wn = wave>>1): 2 M-frags (64 kout) x 4 N-frags (128 px = 8h x 16w).
// Weights: per-cs batch of 18 coalesced fragment loads into regs (zero loads in tap loop).
__global__ __launch_bounds__(256, 2) void conv_mfma(
    const __bf16* __restrict__ xT, const __bf16* __restrict__ wqp,
    const float* __restrict__ gamma, const float* __restrict__ beta,
    const float* __restrict__ mean, const float* __restrict__ var,
    const float* __restrict__ act_scale, const unsigned* __restrict__ wsmax,
    float* __restrict__ out)
{
    __shared__ uint4 xs[2592];                  // 18*18 px * 8 chunks * 16B = 41.5 KB
    __shared__ float sc2[KOUT], sh2[KOUT];

    const int bid = blockIdx.x;                 // n*64 + hb*8 + wb
    const int wb = bid & 7, hb = (bid >> 3) & 7, n = bid >> 6;
    const int h0 = hb * 16, w0 = wb * 16;
    const int tid  = threadIdx.x;
    const int lane = tid & 63;
    const int wave = tid >> 6;
    const int wm = wave & 1;                    // kout half
    const int wn = wave >> 1;                   // pixel-row half

    const float s_act = act_scale[0] / 255.0f;
    if (tid < KOUT) {
        float ws  = __uint_as_float(*wsmax) / 127.0f;
        float isd = 1.0f / sqrtf(var[tid] + BN_EPS);
        float sc  = ws * gamma[tid] * isd;      // fold w_scale into BN scale
        float sh  = beta[tid] - gamma[tid] * mean[tid] * isd;
        sc2[tid] = sc / s_act;                  // q = rint(acc*sc2 + sh2)
        sh2[tid] = sh / s_act;
    }

    // ---- stage halo tile 18x18 px x 64 ch, chunk-xor swizzle (write==read) ----
    const __bf16* xn = xT + (size_t)n * HGT * WID * CIN;
    for (int it = tid; it < 2592; it += 256) {
        int pl = it >> 3, chunk = it & 7;
        int r = pl / 18, cc = pl - r * 18;
        int gh = h0 - 1 + r, gw = w0 - 1 + cc;
        uint4 v = make_uint4(0u, 0u, 0u, 0u);
        if ((unsigned)gh < HGT && (unsigned)gw < WID)
            v = *(const uint4*)(xn + ((size_t)gh * WID + gw) * CIN + chunk * 8);
        xs[pl * 8 + (chunk ^ (pl & 7))] = v;
    }
    __syncthreads();

    const int wl = lane & 15;                   // pixel col
    const int rl = (lane >> 4) & 1;             // pixel row parity within N-frag
    const int kh = lane >> 5;                   // ch-half for A/B operands

    f32x16 acc[2][4];
    #pragma unroll
    for (int a = 0; a < 2; ++a)
        #pragma unroll
        for (int b = 0; b < 4; ++b)
            #pragma unroll
            for (int r = 0; r < 16; ++r) acc[a][b][r] = 0.0f;

    #pragma unroll
    for (int cs = 0; cs < 4; ++cs) {            // channel chunks of 16
        // ---- batch-load this cs-chunk's 18 A-fragments (coalesced, from L2) ----
        bf16x8 a[2][9];
        #pragma unroll
        for (int tap = 0; tap < 9; ++tap) {
            const __bf16* wp = wqp + ((((size_t)cs * 9 + tap) * 4 + wm * 2) * 64 + lane) * 8;
            a[0][tap] = *(const bf16x8*)(wp);
            a[1][tap] = *(const bf16x8*)(wp + 64 * 8);
        }
        const int chb = cs * 2 + kh;
        #pragma unroll
        for (int tap = 0; tap < 9; ++tap) {
            const int dy = tap / 3, dx = tap - dy * 3;
            #pragma unroll
            for (int nf = 0; nf < 4; ++nf) {
                const int pl = (wn * 8 + nf * 2 + rl + dy) * 18 + wl + dx;
                bf16x8 b = *(const bf16x8*)&xs[pl * 8 + (chb ^ (pl & 7))];
                acc[0][nf] = __builtin_amdgcn_mfma_f32_32x32x16_bf16(a[0][tap], b, acc[0][nf], 0, 0, 0);
                acc[1][nf] = __builtin_amdgcn_mfma_f32_32x32x16_bf16(a[1][tap], b, acc[1][nf], 0, 0, 0);
            }
        }
    }

    // ---- epilogue: BN + ReLU + uint8 quant-dequant ----
    const int wpix = w0 + wl;
    #pragma unroll
    for (int mf = 0; mf < 2; ++mf) {
        #pragma unroll
        for (int nf = 0; nf < 4; ++nf) {
            const int hpix = h0 + wn * 8 + nf * 2 + rl;
            #pragma unroll
            for (int reg = 0; reg < 16; ++reg) {
                int k = wm * 64 + mf * 32 + 4 * kh + (reg & 3) + 8 * (reg >> 2);
                float t = fmaf(acc[mf][nf][reg], sc2[k], sh2[k]);
                t = fmaxf(t, 0.0f);                                 // relu
                float q = fminf(rintf(t), 255.0f);
                out[(((size_t)n * KOUT + k) * HGT + hpix) * WID + wpix] = q * s_act;
            }
        }
    }
}

// ---------------- fallback (fp32 path, used only if ws too small) -----------
#define CB 4
#define TH 8
#define KB 8
__global__ __launch_bounds__(256) void conv_fallback(
    const float* __restrict__ x, const float* __restrict__ W,
    const float* __restrict__ gamma, const float* __restrict__ beta,
    const float* __restrict__ mean, const float* __restrict__ var,
    const float* __restrict__ act_scale, const unsigned* __restrict__ wsmax,
    float* __restrict__ out)
{
    __shared__ float xsf[CB][TH + 2][WID + 2];
    __shared__ float wsh[CB][9][KB];
    const int bid = blockIdx.x;
    const int hg = bid & 15, kg = (bid >> 4) & 15, n = bid >> 8;
    const int h0 = hg * TH, k0 = kg * KB;
    const int tid = threadIdx.x;
    const int tx = tid & 31, ty = tid >> 5;
    float acc[4][KB];
    #pragma unroll
    for (int j = 0; j < 4; ++j)
        #pragma unroll
        for (int kk = 0; kk < KB; ++kk) acc[j][kk] = 0.f;
    const float w_scale = __uint_as_float(*wsmax) / 127.0f;
    const float* xn = x + (size_t)n * CIN * HGT * WID;
    for (int c0 = 0; c0 < CIN; c0 += CB) {
        __syncthreads();
        for (int i = tid; i < CB * (TH + 2) * (WID + 2); i += 256) {
            int cc = i / ((TH + 2) * (WID + 2));
            int r  = i - cc * ((TH + 2) * (WID + 2));
            int yy = r / (WID + 2);
            int xx = r - yy * (WID + 2);
            int gh = h0 - 1 + yy, gw = xx - 1;
            float v = 0.f;
            if ((unsigned)gh < HGT && (unsigned)gw < WID)
                v = xn[(size_t)(c0 + cc) * HGT * WID + gh * WID + gw];
            xsf[cc][yy][xx] = v;
        }
        for (int i = tid; i < CB * 9 * KB; i += 256) {
            int cc = i / (9 * KB);
            int r  = i - cc * (9 * KB);
            int tap = r / KB, kk = r - tap * KB;
            float w = W[(size_t)((k0 + kk) * CIN + (c0 + cc)) * 9 + tap];
            float q = rintf(w / w_scale);
            q = fminf(fmaxf(q, -127.f), 127.f);
            wsh[cc][tap][kk] = q * w_scale;
        }
        __syncthreads();
        #pragma unroll
        for (int cc = 0; cc < CB; ++cc)
            #pragma unroll
            for (int dy = 0; dy < 3; ++dy) {
                float w0a[KB], w1a[KB], w2a[KB];
                #pragma unroll
                for (int kk = 0; kk < KB; ++kk) {
                    w0a[kk] = wsh[cc][dy * 3 + 0][kk];
                    w1a[kk] = wsh[cc][dy * 3 + 1][kk];
                    w2a[kk] = wsh[cc][dy * 3 + 2][kk];
                }
                const float* row = &xsf[cc][ty + dy][0];
                #pragma unroll
                for (int j = 0; j < 4; ++j) {
                    float v0 = row[tx + 32 * j + 0];
                    float v1 = row[tx + 32 * j + 1];
                    float v2 = row[tx + 32 * j + 2];
                    #pragma unroll
                    for (int kk = 0; kk < KB; ++kk) {
                        acc[j][kk] = fmaf(v0, w0a[kk], acc[j][kk]);
                        acc[j][kk] = fmaf(v1, w1a[kk], acc[j][kk]);
                        acc[j][kk] = fmaf(v2, w2a[kk], acc[j][kk]);
                    }
                }
            }
    }
    const float s_act = act_scale[0] / 255.0f;
    const float inv_s = 1.0f / s_act;
    const int h = h0 + ty;
    #pragma unroll
    for (int kk = 0; kk < KB; ++kk) {
        int k = k0 + kk;
        float isd = 1.0f / sqrtf(var[k] + BN_EPS);
        float sc = gamma[k] * isd;
        float sh = beta[k] - gamma[k] * mean[k] * isd;
        float* orow = out + (((size_t)n * KOUT + k) * HGT + h) * WID;
        #pragma unroll
        for (int j = 0; j < 4; ++j) {
            float y = fmaf(acc[j][kk], sc, sh);
            y = fmaxf(y, 0.f);
            float q = rintf(y * inv_s);
            q = fminf(q, 255.f);
            orow[tx + 32 * j] = q * s_act;
        }
    }
}

extern "C" void kernel_launch(void* const* d_in, const int* in_sizes, int n_in,
                              void* d_out, int out_size, void* d_ws, size_t ws_size,
                              hipStream_t stream) {
    const float* x         = (const float*)d_in[0];
    const float* W         = (const float*)d_in[1];
    const float* gamma     = (const float*)d_in[2];
    const float* beta      = (const float*)d_in[3];
    const float* mean      = (const float*)d_in[4];
    const float* var       = (const float*)d_in[5];
    const float* act_scale = (const float*)d_in[6];
    unsigned* wsmax = (unsigned*)d_ws;

    hipMemsetAsync(d_ws, 0, sizeof(unsigned), stream);
    wmax_kernel<<<72, 256, 0, stream>>>(W, wsmax);

    if (ws_size >= WS_NEED) {
        __bf16* wqp = (__bf16*)((char*)d_ws + WQ_OFF);
        __bf16* xT  = (__bf16*)((char*)d_ws + XT_OFF);
        pack_w<<<36, 256, 0, stream>>>(W, wsmax, wqp);
        xform<<<NBATCH * HGT * 4, 256, 0, stream>>>(x, xT);
        conv_mfma<<<NBATCH * 64, 256, 0, stream>>>(
            xT, wqp, gamma, beta, mean, var, act_scale, wsmax, (float*)d_out);
    } else {
        conv_fallback<<<4096, 256, 0, stream>>>(
            x, W, gamma, beta, mean, var, act_scale, wsmax, (float*)d_out);
    }
}

// Round 4
// 84.403 us; speedup vs baseline: 9.7235x; 1.0247x over previous
//
#include <hip/hip_runtime.h>
#include <math.h>

typedef __bf16 bf16x8 __attribute__((ext_vector_type(8)));
typedef float  f32x16 __attribute__((ext_vector_type(16)));

#define CIN    64
#define KOUT   128
#define HGT    128
#define WID    128
#define NBATCH 16
#define BN_EPS 1e-5f

// workspace layout
#define WQ_OFF   256u                        // packed frag weights: 36*4*64*16B = 147456 B
#define XT_OFF   (1u << 20)                  // NHWC bf16 x: 16*128*128*64*2 = 33554432 B
#define WS_NEED  ((size_t)XT_OFF + (size_t)NBATCH * HGT * WID * CIN * 2)

// ---------------- w_scale = max|W| ------------------------------------------
__global__ __launch_bounds__(256) void wmax_kernel(const float* __restrict__ W,
                                                   unsigned* __restrict__ wsmax) {
    int idx = blockIdx.x * 256 + threadIdx.x;   // 72*256*4 = 73728 floats
    const float4* W4 = (const float4*)W;
    float4 v = W4[idx];
    float m = fmaxf(fmaxf(fabsf(v.x), fabsf(v.y)), fmaxf(fabsf(v.z), fabsf(v.w)));
    #pragma unroll
    for (int off = 32; off > 0; off >>= 1)
        m = fmaxf(m, __shfl_xor(m, off));
    __shared__ float red[4];
    if ((threadIdx.x & 63) == 0) red[threadIdx.x >> 6] = m;
    __syncthreads();
    if (threadIdx.x == 0) {
        m = fmaxf(fmaxf(red[0], red[1]), fmaxf(red[2], red[3]));
        atomicMax(wsmax, __float_as_uint(m));
    }
}

// ---------------- pack weights into MFMA A-fragment order -------------------
// wqp element base ((cs*9+tap)*4 + mf)*64 + lane  (bf16x8 per lane):
//   j-th elem = Wq[kout = mf*32 + (lane&31)][c = cs*16 + (lane>>5)*8 + j] at tap.
__global__ __launch_bounds__(256) void pack_w(const float* __restrict__ W,
                                              const unsigned* __restrict__ wsmax,
                                              __bf16* __restrict__ wqp) {
    int bid = blockIdx.x;                       // 36 = cs*9 + tap
    int tap = bid % 9, cs = bid / 9;
    int t = threadIdx.x;
    int lane = t & 63, mf = t >> 6;
    float ws = __uint_as_float(*wsmax) / 127.0f;
    int kout  = mf * 32 + (lane & 31);
    int cbase = cs * 16 + (lane >> 5) * 8;
    bf16x8 o;
    #pragma unroll
    for (int j = 0; j < 8; ++j) {
        float w = W[(size_t)(kout * 64 + cbase + j) * 9 + tap];
        float q = rintf(w / ws);                // RNE == jnp.round
        q = fminf(fmaxf(q, -127.f), 127.f);
        o[j] = (__bf16)q;                       // integer: exact in bf16
    }
    *(bf16x8*)(wqp + (((size_t)bid * 4 + mf) * 64 + lane) * 8) = o;
}

// ---------------- x: NCHW f32 -> NHWC bf16 -----------------------------------
__global__ __launch_bounds__(256) void xform(const float* __restrict__ x,
                                             __bf16* __restrict__ xT) {
    __shared__ float t[CIN * 32];               // 8 KB, xor-swizzled cols
    int bid = blockIdx.x;                       // n*512 + h*4 + wt
    int wt = bid & 3;
    int h  = (bid >> 2) & 127;
    int n  = bid >> 9;
    int w0 = wt * 32;
    int tid = threadIdx.x;
    const float* src = x + ((size_t)n * CIN * HGT + h) * WID + w0;
    int wlane = tid & 31;
    int cbase = tid >> 5;
    #pragma unroll
    for (int it = 0; it < 8; ++it) {
        int c = cbase + it * 8;
        t[c * 32 + (wlane ^ (c & 31))] = src[(size_t)c * HGT * WID + wlane];
    }
    __syncthreads();
    int w = tid >> 3;
    int chunk = tid & 7;
    bf16x8 o;
    #pragma unroll
    for (int j = 0; j < 8; ++j) {
        int c = chunk * 8 + j;
        o[j] = (__bf16)t[c * 32 + (w ^ (c & 31))];
    }
    *(bf16x8*)(xT + (((size_t)n * HGT + h) * WID + w0 + w) * CIN + chunk * 8) = o;
}

// ---------------- conv3x3 via MFMA 32x32x16 bf16 ----------------------------
// block: 256 thr = 4 waves; out tile 8h x 32w x 128 kout.
// wave (wm = wave&1, wr = wave>>1): 2 M-frags (64 kout) x 4 N-frags.
// N-frag = ONE output row of 32 cols -> a 6-row x 3-dx register window of B
// (18 batched ds_reads per cs) feeds all 72 MFMAs of the cs chunk (4:1).
__global__ __launch_bounds__(256, 2) void conv_mfma(
    const __bf16* __restrict__ xT, const __bf16* __restrict__ wqp,
    const float* __restrict__ gamma, const float* __restrict__ beta,
    const float* __restrict__ mean, const float* __restrict__ var,
    const float* __restrict__ act_scale, const unsigned* __restrict__ wsmax,
    float* __restrict__ out)
{
    __shared__ uint4 xs[2720];                  // 10 rows * 34 cols * 8 chunks * 16B = 43.5 KB
    __shared__ float sc2[KOUT], sh2[KOUT];

    const int bid = blockIdx.x;                 // n*64 + hb*4 + wb
    const int wb = bid & 3, hb = (bid >> 2) & 15, n = bid >> 6;
    const int h0 = hb * 8, w0 = wb * 32;
    const int tid  = threadIdx.x;
    const int lane = tid & 63;
    const int wave = tid >> 6;
    const int wm = wave & 1;                    // kout half
    const int wr = wave >> 1;                   // row group (4 rows)

    const float s_act = act_scale[0] / 255.0f;
    if (tid < KOUT) {
        float ws  = __uint_as_float(*wsmax) / 127.0f;
        float isd = 1.0f / sqrtf(var[tid] + BN_EPS);
        float sc  = ws * gamma[tid] * isd;      // fold w_scale into BN scale
        float sh  = beta[tid] - gamma[tid] * mean[tid] * isd;
        sc2[tid] = sc / s_act;                  // q = rint(acc*sc2 + sh2)
        sh2[tid] = sh / s_act;
    }

    // ---- stage halo tile 10 x 34 px x 64 ch, chunk-xor swizzle (write==read) ----
    const __bf16* xn = xT + (size_t)n * HGT * WID * CIN;
    for (int it = tid; it < 2720; it += 256) {
        int pl = it >> 3, chunk = it & 7;
        int r = pl / 34, cc = pl - r * 34;
        int gh = h0 - 1 + r, gw = w0 - 1 + cc;
        uint4 v = make_uint4(0u, 0u, 0u, 0u);
        if ((unsigned)gh < HGT && (unsigned)gw < WID)
            v = *(const uint4*)(xn + ((size_t)gh * WID + gw) * CIN + chunk * 8);
        xs[pl * 8 + (chunk ^ (pl & 7))] = v;
    }
    __syncthreads();

    const int nn = lane & 31;                   // pixel col within row-frag
    const int kh = lane >> 5;                   // ch-half for A/B operands

    f32x16 acc[2][4];
    #pragma unroll
    for (int a = 0; a < 2; ++a)
        #pragma unroll
        for (int b = 0; b < 4; ++b)
            #pragma unroll
            for (int r = 0; r < 16; ++r) acc[a][b][r] = 0.0f;

    #pragma unroll
    for (int cs = 0; cs < 4; ++cs) {            // channel chunks of 16
        const int chb = cs * 2 + kh;
        // ---- batched B window: 6 halo rows x 3 dx (18 ds_read_b128) ----
        bf16x8 B[6][3];
        #pragma unroll
        for (int rr = 0; rr < 6; ++rr) {
            #pragma unroll
            for (int dx = 0; dx < 3; ++dx) {
                const int pl = (wr * 4 + rr) * 34 + nn + dx;
                B[rr][dx] = *(const bf16x8*)&xs[pl * 8 + (chb ^ (pl & 7))];
            }
        }
        #pragma unroll
        for (int dy = 0; dy < 3; ++dy) {
            // ---- A for this tap row: 2 mf x 3 dx, coalesced from L2 ----
            bf16x8 A[2][3];
            #pragma unroll
            for (int dx = 0; dx < 3; ++dx) {
                const __bf16* wp = wqp + ((((size_t)cs * 9 + dy * 3 + dx) * 4 + wm * 2) * 64 + lane) * 8;
                A[0][dx] = *(const bf16x8*)(wp);
                A[1][dx] = *(const bf16x8*)(wp + 64 * 8);
            }
            #pragma unroll
            for (int nf = 0; nf < 4; ++nf) {
                #pragma unroll
                for (int dx = 0; dx < 3; ++dx) {
                    acc[0][nf] = __builtin_amdgcn_mfma_f32_32x32x16_bf16(A[0][dx], B[nf + dy][dx], acc[0][nf], 0, 0, 0);
                    acc[1][nf] = __builtin_amdgcn_mfma_f32_32x32x16_bf16(A[1][dx], B[nf + dy][dx], acc[1][nf], 0, 0, 0);
                }
            }
        }
    }

    // ---- epilogue: BN + ReLU + uint8 quant-dequant ----
    const int wpix = w0 + nn;
    #pragma unroll
    for (int mf = 0; mf < 2; ++mf) {
        #pragma unroll
        for (int nf = 0; nf < 4; ++nf) {
            const int hpix = h0 + wr * 4 + nf;
            #pragma unroll
            for (int reg = 0; reg < 16; ++reg) {
                int k = wm * 64 + mf * 32 + 4 * kh + (reg & 3) + 8 * (reg >> 2);
                float t = fmaf(acc[mf][nf][reg], sc2[k], sh2[k]);
                t = fmaxf(t, 0.0f);                                 // relu
                float q = fminf(rintf(t), 255.0f);
                out[(((size_t)n * KOUT + k) * HGT + hpix) * WID + wpix] = q * s_act;
            }
        }
    }
}

// ---------------- fallback (fp32 path, used only if ws too small) -----------
#define CB 4
#define TH 8
#define KB 8
__global__ __launch_bounds__(256) void conv_fallback(
    const float* __restrict__ x, const float* __restrict__ W,
    const float* __restrict__ gamma, const float* __restrict__ beta,
    const float* __restrict__ mean, const float* __restrict__ var,
    const float* __restrict__ act_scale, const unsigned* __restrict__ wsmax,
    float* __restrict__ out)
{
    __shared__ float xsf[CB][TH + 2][WID + 2];
    __shared__ float wsh[CB][9][KB];
    const int bid = blockIdx.x;
    const int hg = bid & 15, kg = (bid >> 4) & 15, n = bid >> 8;
    const int h0 = hg * TH, k0 = kg * KB;
    const int tid = threadIdx.x;
    const int tx = tid & 31, ty = tid >> 5;
    float acc[4][KB];
    #pragma unroll
    for (int j = 0; j < 4; ++j)
        #pragma unroll
        for (int kk = 0; kk < KB; ++kk) acc[j][kk] = 0.f;
    const float w_scale = __uint_as_float(*wsmax) / 127.0f;
    const float* xn = x + (size_t)n * CIN * HGT * WID;
    for (int c0 = 0; c0 < CIN; c0 += CB) {
        __syncthreads();
        for (int i = tid; i < CB * (TH + 2) * (WID + 2); i += 256) {
            int cc = i / ((TH + 2) * (WID + 2));
            int r  = i - cc * ((TH + 2) * (WID + 2));
            int yy = r / (WID + 2);
            int xx = r - yy * (WID + 2);
            int gh = h0 - 1 + yy, gw = xx - 1;
            float v = 0.f;
            if ((unsigned)gh < HGT && (unsigned)gw < WID)
                v = xn[(size_t)(c0 + cc) * HGT * WID + gh * WID + gw];
            xsf[cc][yy][xx] = v;
        }
        for (int i = tid; i < CB * 9 * KB; i += 256) {
            int cc = i / (9 * KB);
            int r  = i - cc * (9 * KB);
            int tap = r / KB, kk = r - tap * KB;
            float w = W[(size_t)((k0 + kk) * CIN + (c0 + cc)) * 9 + tap];
            float q = rintf(w / w_scale);
            q = fminf(fmaxf(q, -127.f), 127.f);
            wsh[cc][tap][kk] = q * w_scale;
        }
        __syncthreads();
        #pragma unroll
        for (int cc = 0; cc < CB; ++cc)
            #pragma unroll
            for (int dy = 0; dy < 3; ++dy) {
                float w0a[KB], w1a[KB], w2a[KB];
                #pragma unroll
                for (int kk = 0; kk < KB; ++kk) {
                    w0a[kk] = wsh[cc][dy * 3 + 0][kk];
                    w1a[kk] = wsh[cc][dy * 3 + 1][kk];
                    w2a[kk] = wsh[cc][dy * 3 + 2][kk];
                }
                const float* row = &xsf[cc][ty + dy][0];
                #pragma unroll
                for (int j = 0; j < 4; ++j) {
                    float v0 = row[tx + 32 * j + 0];
                    float v1 = row[tx + 32 * j + 1];
                    float v2 = row[tx + 32 * j + 2];
                    #pragma unroll
                    for (int kk = 0; kk < KB; ++kk) {
                        acc[j][kk] = fmaf(v0, w0a[kk], acc[j][kk]);
                        acc[j][kk] = fmaf(v1, w1a[kk], acc[j][kk]);
                        acc[j][kk] = fmaf(v2, w2a[kk], acc[j][kk]);
                    }
                }
            }
    }
    const float s_act = act_scale[0] / 255.0f;
    const float inv_s = 1.0f / s_act;
    const int h = h0 + ty;
    #pragma unroll
    for (int kk = 0; kk < KB; ++kk) {
        int k = k0 + kk;
        float isd = 1.0f / sqrtf(var[k] + BN_EPS);
        float sc = gamma[k] * isd;
        float sh = beta[k] - gamma[k] * mean[k] * isd;
        float* orow = out + (((size_t)n * KOUT + k) * HGT + h) * WID;
        #pragma unroll
        for (int j = 0; j < 4; ++j) {
            float y = fmaf(acc[j][kk], sc, sh);
            y = fmaxf(y, 0.f);
            float q = rintf(y * inv_s);
            q = fminf(q, 255.f);
            orow[tx + 32 * j] = q * s_act;
        }
    }
}

extern "C" void kernel_launch(void* const* d_in, const int* in_sizes, int n_in,
                              void* d_out, int out_size, void* d_ws, size_t ws_size,
                              hipStream_t stream) {
    const float* x         = (const float*)d_in[0];
    const float* W         = (const float*)d_in[1];
    const float* gamma     = (const float*)d_in[2];
    const float* beta      = (const float*)d_in[3];
    const float* mean      = (const float*)d_in[4];
    const float* var       = (const float*)d_in[5];
    const float* act_scale = (const float*)d_in[6];
    unsigned* wsmax = (unsigned*)d_ws;

    hipMemsetAsync(d_ws, 0, sizeof(unsigned), stream);
    wmax_kernel<<<72, 256, 0, stream>>>(W, wsmax);

    if (ws_size >= WS_NEED) {
        __bf16* wqp = (__bf16*)((char*)d_ws + WQ_OFF);
        __bf16* xT  = (__bf16*)((char*)d_ws + XT_OFF);
        pack_w<<<36, 256, 0, stream>>>(W, wsmax, wqp);
        xform<<<NBATCH * HGT * 4, 256, 0, stream>>>(x, xT);
        conv_mfma<<<NBATCH * 64, 256, 0, stream>>>(
            xT, wqp, gamma, beta, mean, var, act_scale, wsmax, (float*)d_out);
    } else {
        conv_fallback<<<4096, 256, 0, stream>>>(
            x, W, gamma, beta, mean, var, act_scale, wsmax, (float*)d_out);
    }
}